// Round 7
// baseline (663.575 us; speedup 1.0000x reference)
//
#include <hip/hip_runtime.h>
#include <hip/hip_bf16.h>

// GAT fused forward loss.
// e_ij = lrelu(s_i + d_j) is rank-1 => flash-style masked softmax aggregation
// with P built on the fly in bf16, P@Wh via MFMA 16x16x32.
// relu(elu(x)) == relu(x); no softmax max-shift needed (|s+d| < ~8).
// R7: adj read is at the ~3.35 TB/s one-directional read ceiling (3 patterns
// identical; fill=6.9 TB/s write, copy=3.15+3.15). => FUSE pack+attn so the
// attn compute hides UNDER the mandatory 537MB read: block owns 16 rows,
// 16 dbuf steps of 512 j {coop nt-load 32KB -> pack u32 masks in LDS ->
// barrier -> 4 waves MFMA their 128-j windows}, block-level LDS reduction
// writes FINAL numP/zP (no mask round-trip, no SC partial pass).

#define NN 8192
#define FTDIM 512
#define CDIM 64
#define NTRAIN 1024
#define LOG2E 1.44269504088896f
#define JSTEP 512
#define NSTEPS (NN / JSTEP)   // 16
#define WJ 128                // j-window per wave per step

typedef __attribute__((ext_vector_type(8))) short short8;
typedef __attribute__((ext_vector_type(4))) float f32x4;
typedef __attribute__((ext_vector_type(4))) int i32x4;

static __device__ __forceinline__ unsigned short f2bf(float x) {
    return __bfloat16_as_ushort(__float2bfloat16(x));
}

// ---------------------------------------------------------------------------
// Kernel A: Wh = feat @ W. Each wave computes 8 rows (one j-block), lane c
// owns column c. Writes Vt2[jblk][c][e] = bf16(Wh[jblk*8+e][c]) (contiguous
// 256B per 16-lane B-fragment group downstream). Stores factored-exp tables:
//   sQ[i] = (E1, E2, th) = (2^s', 2^(0.2 s'), 2^(-s'))
//   dE[j] = (e1, e2)     = (2^d', 2^(0.2 d'))     with s',d' = log2e-scaled.
// Then P = (e1 > th) ? E1*e1 : E2*e2  ==  exp(lrelu(s+d)) exactly.
// ---------------------------------------------------------------------------
__global__ __launch_bounds__(256) void k_wh(
    const float* __restrict__ feat, const float* __restrict__ W,
    const float* __restrict__ av, unsigned short* __restrict__ Vt2,
    float4* __restrict__ sQ, float2* __restrict__ dE)
{
    const int lane = threadIdx.x & 63;
    const int wv   = (int)((blockIdx.x * blockDim.x + threadIdx.x) >> 6);
    const int row0 = wv * 8;
    const int c    = lane;

    float acc[8];
#pragma unroll
    for (int r = 0; r < 8; ++r) acc[r] = 0.f;

    for (int k = 0; k < FTDIM; k += 4) {
        f32x4 f[8];
#pragma unroll
        for (int r = 0; r < 8; ++r)
            f[r] = *(const f32x4*)(feat + (size_t)(row0 + r) * FTDIM + k);
#pragma unroll
        for (int kk = 0; kk < 4; ++kk) {
            float wval = W[(k + kk) * CDIM + c];
#pragma unroll
            for (int r = 0; r < 8; ++r)
                acc[r] = fmaf(f[r][kk], wval, acc[r]);
        }
    }

    short8 v;
#pragma unroll
    for (int r = 0; r < 8; ++r) v[r] = (short)f2bf(acc[r]);
    *(short8*)(Vt2 + (size_t)wv * 512 + c * 8) = v;   // [jblk][c][8]

    const float a1 = av[c], a2 = av[CDIM + c];
#pragma unroll
    for (int r = 0; r < 8; ++r) {
        float s_ = acc[r] * a1;
        float d_ = acc[r] * a2;
#pragma unroll
        for (int off = 32; off; off >>= 1) {
            s_ += __shfl_xor(s_, off);
            d_ += __shfl_xor(d_, off);
        }
        if (lane == 0) {
            const float sp = s_ * LOG2E, dp_ = d_ * LOG2E;
            sQ[row0 + r] = make_float4(__builtin_amdgcn_exp2f(sp),
                                       __builtin_amdgcn_exp2f(0.2f * sp),
                                       __builtin_amdgcn_exp2f(-sp), 0.f);
            dE[row0 + r] = make_float2(__builtin_amdgcn_exp2f(dp_),
                                       __builtin_amdgcn_exp2f(0.2f * dp_));
        }
    }
}

// ---------------------------------------------------------------------------
// Kernel F: fused adj-read + masked-softmax aggregation.
// Grid 1024 = 2 layers x 512 row-blocks; block = 256 threads (4 waves) owns
// 16 rows. Per step s (16 steps of 512 j, double-buffered LDS masks):
//   stage: thread t nt-loads 32 contiguous ints of row (t>>4), seg (t&15)
//          (8x dwordx4, 128B contiguous; the only HBM-heavy stream, read
//          once) -> packs one u32 mask -> msk[buf][row][seg] (pad 17).
//   compute: wave w handles j-window [s*512+w*128, +128): 4 tiles of 32 j;
//          per tile: 1 LDS mask word (kg lanes broadcast, 16 rows distinct
//          banks) + 4 dE f32x4 + 4 Vt2 short8 (L2-hot; nt on adj keeps them
//          resident); P = bit ? (e1>th ? E1*e1 : E2*e2) : 0 in bf16 A-frag;
//          4 MFMAs numerator + 1 MFMA vs ones = row-sum Z.
// Loads for s+1 issue before compute(s) -> HBM latency hides under MFMA.
// Epilogue: block-level LDS reduction -> FINAL numP[l][i][c], zP[l][i].
// Fragment layouts verified in R1.
// ---------------------------------------------------------------------------
__global__ __launch_bounds__(256, 4) void k_fused(
    const int* __restrict__ adj1, const int* __restrict__ adj2,
    const unsigned short* __restrict__ Vt2, const float4* __restrict__ sQ,
    const float2* __restrict__ dE, float* __restrict__ numP,
    float* __restrict__ zP)
{
    __shared__ unsigned msk[2][16][17];
    __shared__ float red[4][16][66];
    __shared__ float redz[4][16];

    const int tid   = threadIdx.x;
    const int lane  = tid & 63;
    const int wv    = tid >> 6;
    const int bid   = blockIdx.x;
    const int layer = bid >> 9;
    const int rb    = bid & 511;
    const int i0    = rb * 16;

    const int* __restrict__ adj = layer ? adj2 : adj1;
    const int srow = tid >> 4;
    const int sseg = tid & 15;
    const int* __restrict__ srcb = adj + (size_t)(i0 + srow) * NN + sseg * 32;

    const int r  = lane & 15;
    const int kg = lane >> 4;
    const float4 sq = sQ[i0 + r];
    const float E1 = sq.x, E2 = sq.y, th = sq.z;

    short8 bOnes;
#pragma unroll
    for (int e = 0; e < 8; ++e) bOnes[e] = (short)0x3F80;   // bf16 1.0

    f32x4 acc0 = {0.f, 0.f, 0.f, 0.f};
    f32x4 acc1 = acc0, acc2 = acc0, acc3 = acc0, accz = acc0;

    i32x4 st[8];

#define LOADS(S) do {                                                          \
    const i32x4* _p = (const i32x4*)(srcb + (S) * JSTEP);                      \
    _Pragma("unroll")                                                          \
    for (int q = 0; q < 8; ++q) st[q] = __builtin_nontemporal_load(_p + q);    \
} while (0)

#define PSTORE(BUF) do { unsigned _m = 0;                                      \
    _Pragma("unroll")                                                          \
    for (int q = 0; q < 8; ++q) {                                              \
        _m |= (st[q][0] != 0 ? 1u : 0u) << (q * 4);                            \
        _m |= (st[q][1] != 0 ? 1u : 0u) << (q * 4 + 1);                        \
        _m |= (st[q][2] != 0 ? 1u : 0u) << (q * 4 + 2);                        \
        _m |= (st[q][3] != 0 ? 1u : 0u) << (q * 4 + 3);                        \
    }                                                                          \
    msk[BUF][srow][sseg] = _m;                                                 \
} while (0)

#define COMP(BUF, S) do {                                                      \
    const int _jw0 = (S) * JSTEP + wv * WJ;                                    \
    _Pragma("unroll")                                                          \
    for (int jt = 0; jt < 4; ++jt) {                                           \
        const int jabs = _jw0 + jt * 32 + kg * 8;                              \
        const unsigned _w = msk[BUF][r][wv * 4 + jt];                          \
        const unsigned ms = (_w >> (kg * 8)) & 0xffu;                          \
        const f32x4* _dp = (const f32x4*)(dE + jabs);                          \
        f32x4 q0 = _dp[0], q1 = _dp[1], q2 = _dp[2], q3 = _dp[3];              \
        const unsigned short* _vp = Vt2 + (((size_t)jabs >> 3) << 9) + (r<<3); \
        short8 b0 = *(const short8*)(_vp);                                     \
        short8 b1 = *(const short8*)(_vp + 128);                               \
        short8 b2 = *(const short8*)(_vp + 256);                               \
        short8 b3 = *(const short8*)(_vp + 384);                               \
        short8 af;                                                             \
        _Pragma("unroll")                                                      \
        for (int e = 0; e < 8; ++e) {                                          \
            float e1, e2;                                                      \
            switch (e >> 1) {                                                  \
                case 0: e1 = q0[(e&1)*2]; e2 = q0[(e&1)*2+1]; break;           \
                case 1: e1 = q1[(e&1)*2]; e2 = q1[(e&1)*2+1]; break;           \
                case 2: e1 = q2[(e&1)*2]; e2 = q2[(e&1)*2+1]; break;           \
                default: e1 = q3[(e&1)*2]; e2 = q3[(e&1)*2+1]; break;          \
            }                                                                  \
            const bool pos = e1 > th;                                          \
            float pv = (pos ? e1 : e2) * (pos ? E1 : E2);                      \
            pv = ((ms >> e) & 1u) ? pv : 0.f;                                  \
            af[e] = (short)f2bf(pv);                                           \
        }                                                                      \
        acc0 = __builtin_amdgcn_mfma_f32_16x16x32_bf16(af, b0, acc0, 0, 0, 0); \
        acc1 = __builtin_amdgcn_mfma_f32_16x16x32_bf16(af, b1, acc1, 0, 0, 0); \
        acc2 = __builtin_amdgcn_mfma_f32_16x16x32_bf16(af, b2, acc2, 0, 0, 0); \
        acc3 = __builtin_amdgcn_mfma_f32_16x16x32_bf16(af, b3, acc3, 0, 0, 0); \
        accz = __builtin_amdgcn_mfma_f32_16x16x32_bf16(af, bOnes, accz,0,0,0); \
    }                                                                          \
} while (0)

    LOADS(0);
    PSTORE(0);
    __syncthreads();

    for (int s = 0; s < NSTEPS; ++s) {
        if (s + 1 < NSTEPS) LOADS(s + 1);
        COMP(s & 1, s);
        if (s + 1 < NSTEPS) {
            PSTORE((s + 1) & 1);       // writes the OTHER buffer: safe pre-barrier
            __syncthreads();           // masks visible before next step's reads
        }
    }
#undef LOADS
#undef PSTORE
#undef COMP

    // ---- block-level reduction: 4 wave-partials -> final numP, zP ----
#pragma unroll
    for (int q = 0; q < 4; ++q) {
        const int row = kg * 4 + q;
        red[wv][row][r]      = acc0[q];
        red[wv][row][16 + r] = acc1[q];
        red[wv][row][32 + r] = acc2[q];
        red[wv][row][48 + r] = acc3[q];
        if (r == 0) redz[wv][row] = accz[q];
    }
    __syncthreads();

    const int frow = tid >> 4;          // 0..15
    const int fc0  = (tid & 15) * 4;    // 0..60
    float4 o;
    o.x = red[0][frow][fc0]     + red[1][frow][fc0]     + red[2][frow][fc0]     + red[3][frow][fc0];
    o.y = red[0][frow][fc0 + 1] + red[1][frow][fc0 + 1] + red[2][frow][fc0 + 1] + red[3][frow][fc0 + 1];
    o.z = red[0][frow][fc0 + 2] + red[1][frow][fc0 + 2] + red[2][frow][fc0 + 2] + red[3][frow][fc0 + 2];
    o.w = red[0][frow][fc0 + 3] + red[1][frow][fc0 + 3] + red[2][frow][fc0 + 3] + red[3][frow][fc0 + 3];
    *(float4*)(numP + ((size_t)(layer * NN + i0 + frow)) * CDIM + fc0) = o;

    if (tid < 16)
        zP[(size_t)layer * NN + i0 + tid] =
            redz[0][tid] + redz[1][tid] + redz[2][tid] + redz[3][tid];
}

// ---------------------------------------------------------------------------
// Kernel C: per-training-sample loss. One wave per sample, lane = class.
// h = 0.5*(relu(n1/z1) + relu(n2/z2)); log-softmax over 64 lanes; NLL.
// ---------------------------------------------------------------------------
__global__ __launch_bounds__(256) void k_loss(
    const float* __restrict__ numP, const float* __restrict__ zP,
    const int* __restrict__ labels, const int* __restrict__ idxt,
    float* __restrict__ losses)
{
    const int lane = threadIdx.x & 63;
    const int k = (int)((blockIdx.x * blockDim.x + threadIdx.x) >> 6);
    const int i = idxt[k];

    const float n1 = numP[(size_t)i * CDIM + lane];
    const float n2 = numP[((size_t)NN + i) * CDIM + lane];
    const float z1 = zP[i];
    const float z2 = zP[NN + i];
    const float logit = 0.5f * (fmaxf(n1 / z1, 0.f) + fmaxf(n2 / z2, 0.f));

    float m = logit;
#pragma unroll
    for (int off = 32; off; off >>= 1) m = fmaxf(m, __shfl_xor(m, off));
    float ex = __expf(logit - m);
    float sum = ex;
#pragma unroll
    for (int off = 32; off; off >>= 1) sum += __shfl_xor(sum, off);
    const float logp = logit - m - __logf(sum);

    const int y = labels[i];
    const float t = __shfl(logp, y);
    if (lane == 0) losses[k] = -t;
}

// ---------------------------------------------------------------------------
// Kernel D: mean of 1024 per-sample losses -> d_out[0].
// ---------------------------------------------------------------------------
__global__ __launch_bounds__(256) void k_reduce(
    const float* __restrict__ losses, float* __restrict__ out)
{
    __shared__ float sbuf[4];
    const int tid = threadIdx.x;
    float v = losses[tid] + losses[tid + 256] + losses[tid + 512] + losses[tid + 768];
#pragma unroll
    for (int off = 32; off; off >>= 1) v += __shfl_xor(v, off);
    if ((tid & 63) == 0) sbuf[tid >> 6] = v;
    __syncthreads();
    if (tid == 0) out[0] = (sbuf[0] + sbuf[1] + sbuf[2] + sbuf[3]) * (1.f / 1024.f);
}

// ---------------------------------------------------------------------------
extern "C" void kernel_launch(void* const* d_in, const int* in_sizes, int n_in,
                              void* d_out, int out_size, void* d_ws, size_t ws_size,
                              hipStream_t stream)
{
    const float* feat   = (const float*)d_in[0];
    const float* W      = (const float*)d_in[1];
    const float* av     = (const float*)d_in[2];
    const int*   adj1   = (const int*)d_in[3];
    const int*   adj2   = (const int*)d_in[4];
    const int*   labels = (const int*)d_in[5];
    const int*   idxt   = (const int*)d_in[6];

    // ws layout (total ~5.5 MB; harness provides far more):
    char* ws = (char*)d_ws;
    unsigned short* Vt2 = (unsigned short*)ws;                       // 1 MB
    float4* sQ  = (float4*)(ws + (1u << 20));                        // 128 KB
    float2* dEv = (float2*)(ws + (1u << 20) + (128u << 10));         // 64 KB
    float*  numP = (float*)(ws + (1u << 20) + (192u << 10));         // 4 MB
    float*  zP   = numP + 2ull * NN * CDIM;                          // 64 KB
    float*  losses = zP + 2 * NN;                                    // 4 KB

    hipLaunchKernelGGL(k_wh, dim3(256), dim3(256), 0, stream,
                       feat, W, av, Vt2, sQ, dEv);
    hipLaunchKernelGGL(k_fused, dim3(1024), dim3(256), 0, stream,
                       adj1, adj2, Vt2, sQ, dEv, numP, zP);
    hipLaunchKernelGGL(k_loss, dim3(NTRAIN / 4), dim3(256), 0, stream,
                       numP, zP, labels, idxt, losses);
    hipLaunchKernelGGL(k_reduce, dim3(1), dim3(256), 0, stream,
                       losses, (float*)d_out);
}

// Round 8
// 262.748 us; speedup vs baseline: 2.5255x; 2.5255x over previous
//
#include <hip/hip_runtime.h>
#include <hip/hip_bf16.h>

// GAT fused forward loss.
// e_ij = lrelu(s_i + d_j) is rank-1 => flash-style masked softmax aggregation
// with P built on the fly in bf16, P@Wh via MFMA 16x16x32.
// relu(elu(x)) == relu(x); no softmax max-shift needed (|s+d| < ~8).
// R8: REVERT R7 fusion (L3 thrash: FETCH 1.37GB, Vt2 evicted by adj stream).
//     Back to R5 structure. k_attn: (256,7), u64 mask loads, 64 j/iter.

#define NN 8192
#define FTDIM 512
#define CDIM 64
#define NTRAIN 1024
#define LOG2E 1.44269504088896f

typedef __attribute__((ext_vector_type(8))) short short8;
typedef __attribute__((ext_vector_type(4))) float f32x4;
typedef __attribute__((ext_vector_type(4))) int i32x4;

static __device__ __forceinline__ unsigned short f2bf(float x) {
    return __bfloat16_as_ushort(__float2bfloat16(x));
}

// ---------------------------------------------------------------------------
// Kernel A: Wh = feat @ W. Each wave computes 8 rows (one j-block), lane c
// owns column c. Writes Vt2[jblk][c][e] = bf16(Wh[jblk*8+e][c]) and the
// factored-exp tables:
//   sQ[i] = (E1, E2, th) = (2^s', 2^(0.2 s'), 2^(-s'))
//   dE[j] = (e1, e2)     = (2^d', 2^(0.2 d'))     (s',d' log2e-scaled)
// P = (e1 > th) ? E1*e1 : E2*e2 == exp(lrelu(s+d)) exactly.
// ---------------------------------------------------------------------------
__global__ __launch_bounds__(256) void k_wh(
    const float* __restrict__ feat, const float* __restrict__ W,
    const float* __restrict__ av, unsigned short* __restrict__ Vt2,
    float4* __restrict__ sQ, float2* __restrict__ dE)
{
    const int lane = threadIdx.x & 63;
    const int wv   = (int)((blockIdx.x * blockDim.x + threadIdx.x) >> 6);
    const int row0 = wv * 8;
    const int c    = lane;

    float acc[8];
#pragma unroll
    for (int r = 0; r < 8; ++r) acc[r] = 0.f;

    for (int k = 0; k < FTDIM; k += 4) {
        f32x4 f[8];
#pragma unroll
        for (int r = 0; r < 8; ++r)
            f[r] = *(const f32x4*)(feat + (size_t)(row0 + r) * FTDIM + k);
#pragma unroll
        for (int kk = 0; kk < 4; ++kk) {
            float wval = W[(k + kk) * CDIM + c];
#pragma unroll
            for (int r = 0; r < 8; ++r)
                acc[r] = fmaf(f[r][kk], wval, acc[r]);
        }
    }

    short8 v;
#pragma unroll
    for (int r = 0; r < 8; ++r) v[r] = (short)f2bf(acc[r]);
    *(short8*)(Vt2 + (size_t)wv * 512 + c * 8) = v;   // [jblk][c][8]

    const float a1 = av[c], a2 = av[CDIM + c];
#pragma unroll
    for (int r = 0; r < 8; ++r) {
        float s_ = acc[r] * a1;
        float d_ = acc[r] * a2;
#pragma unroll
        for (int off = 32; off; off >>= 1) {
            s_ += __shfl_xor(s_, off);
            d_ += __shfl_xor(d_, off);
        }
        if (lane == 0) {
            const float sp = s_ * LOG2E, dp_ = d_ * LOG2E;
            sQ[row0 + r] = make_float4(__builtin_amdgcn_exp2f(sp),
                                       __builtin_amdgcn_exp2f(0.2f * sp),
                                       __builtin_amdgcn_exp2f(-sp), 0.f);
            dE[row0 + r] = make_float2(__builtin_amdgcn_exp2f(dp_),
                                       __builtin_amdgcn_exp2f(0.2f * dp_));
        }
    }
}

// ---------------------------------------------------------------------------
// Kernel P (R5 version -- at the measured ~3.35 TB/s effective read wall):
// grid 4096, 8 fixed iters/wave, unroll 4 -> 16 dwordx4 outstanding.
// Per iter: 1024 consecutive ints -> 64 u16 masks stored coalesced.
// Bit b of u32 word w == adj_flat[w*32 + b].
// ---------------------------------------------------------------------------
__global__ __launch_bounds__(256, 4) void k_pack(
    const int* __restrict__ adj1, const int* __restrict__ adj2,
    unsigned short* __restrict__ maskB)
{
    const int lane = threadIdx.x & 63;
    const int wv = (int)((blockIdx.x * blockDim.x + threadIdx.x) >> 6);
    const long long NSQ = (long long)NN * NN;          // 2^26

#pragma unroll 4
    for (int u = 0; u < 8; ++u) {
        const long long it = (long long)wv + (long long)u * 16384;
        const long long base = it << 10;
        const int* __restrict__ src = (base < NSQ) ? adj1 : adj2;
        const long long lbase = (base & (NSQ - 1)) + (long long)lane * 16;

        i32x4 a0 = *(const i32x4*)(src + lbase);
        i32x4 a1 = *(const i32x4*)(src + lbase + 4);
        i32x4 a2 = *(const i32x4*)(src + lbase + 8);
        i32x4 a3 = *(const i32x4*)(src + lbase + 12);

        unsigned m = 0;
#pragma unroll
        for (int e = 0; e < 4; ++e) {
            m |= (a0[e] != 0 ? 1u : 0u) << e;
            m |= (a1[e] != 0 ? 1u : 0u) << (4 + e);
            m |= (a2[e] != 0 ? 1u : 0u) << (8 + e);
            m |= (a3[e] != 0 ? 1u : 0u) << (12 + e);
        }
        maskB[(base >> 4) + lane] = (unsigned short)m;
    }
}

// ---------------------------------------------------------------------------
// Kernel B: fused masked-softmax aggregation on the bitmask (raw-adj
// fallback). Wave owns 16 rows x one j-chunk (SC=8 -> 8192 waves; (256,7)
// -> 7 waves/SIMD). Per iteration: 64 j = 1 u64 mask load + 2 half-tiles of
// {4 dE f32x4 + 4 Vt2 short8 + 5 MFMA}. P = bit ? (e1>th ? E1*e1 : E2*e2)
// : 0 (factored exp, no transcendental). Z via MFMA with B=ones.
// Fragment layouts verified in R1.
// ---------------------------------------------------------------------------
template<bool USEMASK>
__global__ __launch_bounds__(256, 7) void k_attn(
    const int* __restrict__ adj1, const int* __restrict__ adj2,
    const unsigned* __restrict__ maskW,
    const unsigned short* __restrict__ Vt2, const float4* __restrict__ sQ,
    const float2* __restrict__ dE, float* __restrict__ numP,
    float* __restrict__ zP, const int scLog2)
{
    const int lane = threadIdx.x & 63;
    const int w = (int)((blockIdx.x * blockDim.x + threadIdx.x) >> 6);
    const int layer = w >> (9 + scLog2);
    const int rem = w & ((1 << (9 + scLog2)) - 1);
    const int rb = rem >> scLog2;
    const int sc = rem & ((1 << scLog2) - 1);

    const int r  = lane & 15;
    const int kg = lane >> 4;
    const int i  = rb * 16 + r;

    const int jchunk = NN >> scLog2;          // >= 1024
    const int jbase  = sc * jchunk + kg * 8;
    const int niter  = jchunk >> 6;           // 64 j per iter

    const int* __restrict__ adj = (layer == 0) ? adj1 : adj2;
    const int*            arow  = adj + (size_t)i * NN + jbase;
    const unsigned long long* mrow64 =
        (const unsigned long long*)(maskW + (size_t)(layer * NN + i) * (NN >> 5)
                                          + sc * (jchunk >> 5));
    const float*          dEf   = (const float*)dE;     // flat f32 view
    const unsigned short* vt2p  = Vt2 + (((size_t)jbase >> 3) << 9) + ((size_t)r << 3);

    const float4 sq = sQ[i];
    const float E1 = sq.x, E2 = sq.y, th = sq.z;

    short8 bOnes;
#pragma unroll
    for (int e = 0; e < 8; ++e) bOnes[e] = (short)0x3F80;   // bf16 1.0

    f32x4 acc0 = {0.f, 0.f, 0.f, 0.f};
    f32x4 acc1 = acc0, acc2 = acc0, acc3 = acc0, accz = acc0;

    for (int jt = 0; jt < niter; ++jt) {
        unsigned long long mw = 0;
        i32x4 m0, m1;
        if constexpr (USEMASK) mw = mrow64[jt];

#pragma unroll
        for (int half = 0; half < 2; ++half) {
            const int joff = jt * 64 + half * 32;            // rel to jbase
            if constexpr (!USEMASK) {
                m0 = *(const i32x4*)(arow + joff);
                m1 = *(const i32x4*)(arow + joff + 4);
            }
            // lane's 8 (e1,e2) pairs: dE[jbase + joff .. +8)
            const f32x4* dp = (const f32x4*)(dEf + 2 * ((size_t)jbase + joff));
            f32x4 q0 = dp[0], q1 = dp[1], q2 = dp[2], q3 = dp[3];
            const unsigned short* vp = vt2p + ((size_t)(jt * 8 + half * 4) << 9);
            short8 b0 = *(const short8*)(vp);
            short8 b1 = *(const short8*)(vp + 128);
            short8 b2 = *(const short8*)(vp + 256);
            short8 b3 = *(const short8*)(vp + 384);

            const unsigned ms = USEMASK
                ? (unsigned)(mw >> (half * 32 + kg * 8)) & 0xffu : 0u;
            short8 af;
#pragma unroll
            for (int e = 0; e < 8; ++e) {
                float e1, e2;
                switch (e >> 1) {
                    case 0: e1 = q0[(e&1)*2]; e2 = q0[(e&1)*2+1]; break;
                    case 1: e1 = q1[(e&1)*2]; e2 = q1[(e&1)*2+1]; break;
                    case 2: e1 = q2[(e&1)*2]; e2 = q2[(e&1)*2+1]; break;
                    default: e1 = q3[(e&1)*2]; e2 = q3[(e&1)*2+1]; break;
                }
                const bool pos = e1 > th;                 // <=> s'+d' > 0
                float p = (pos ? e1 : e2) * (pos ? E1 : E2);
                const bool on = USEMASK ? (((ms >> e) & 1u) != 0u)
                                        : ((e < 4 ? m0[e] : m1[e - 4]) != 0);
                p = on ? p : 0.f;
                af[e] = (short)f2bf(p);
            }

            acc0 = __builtin_amdgcn_mfma_f32_16x16x32_bf16(af, b0, acc0, 0, 0, 0);
            acc1 = __builtin_amdgcn_mfma_f32_16x16x32_bf16(af, b1, acc1, 0, 0, 0);
            acc2 = __builtin_amdgcn_mfma_f32_16x16x32_bf16(af, b2, acc2, 0, 0, 0);
            acc3 = __builtin_amdgcn_mfma_f32_16x16x32_bf16(af, b3, acc3, 0, 0, 0);
            accz = __builtin_amdgcn_mfma_f32_16x16x32_bf16(af, bOnes, accz, 0, 0, 0);
        }
    }

    const size_t chunkbase = (size_t)((layer << scLog2) + sc) * NN;
    const int orow0 = rb * 16 + kg * 4;

    // accz[q] = Z of row (kg*4+q), identical across the 16 col-lanes.
    if (r == 0) {
#pragma unroll
        for (int q = 0; q < 4; ++q) zP[chunkbase + orow0 + q] = accz[q];
    }

#pragma unroll
    for (int q = 0; q < 4; ++q) {
        float* op = numP + (chunkbase + orow0 + q) * CDIM + r;
        op[0]  = acc0[q];
        op[16] = acc1[q];
        op[32] = acc2[q];
        op[48] = acc3[q];
    }
}

template __global__ void k_attn<true>(const int*, const int*, const unsigned*,
    const unsigned short*, const float4*, const float2*, float*, float*, const int);
template __global__ void k_attn<false>(const int*, const int*, const unsigned*,
    const unsigned short*, const float4*, const float2*, float*, float*, const int);

// ---------------------------------------------------------------------------
// Kernel C: per-training-sample loss. One wave per sample, lane = class.
// ---------------------------------------------------------------------------
__global__ __launch_bounds__(256) void k_loss(
    const float* __restrict__ numP, const float* __restrict__ zP,
    const int* __restrict__ labels, const int* __restrict__ idxt,
    float* __restrict__ losses, const int SC)
{
    const int lane = threadIdx.x & 63;
    const int k = (int)((blockIdx.x * blockDim.x + threadIdx.x) >> 6);
    const int i = idxt[k];

    float logit = 0.f;
#pragma unroll
    for (int l = 0; l < 2; ++l) {
        float nsum = 0.f, zsum = 0.f;
        for (int s = 0; s < SC; ++s) {
            size_t b = (size_t)(l * SC + s) * NN + i;
            nsum += numP[b * CDIM + lane];
            zsum += zP[b];
        }
        logit += fmaxf(nsum / zsum, 0.f);   // relu(elu(x)) == relu(x)
    }
    logit *= 0.5f;

    float m = logit;
#pragma unroll
    for (int off = 32; off; off >>= 1) m = fmaxf(m, __shfl_xor(m, off));
    float ex = __expf(logit - m);
    float sum = ex;
#pragma unroll
    for (int off = 32; off; off >>= 1) sum += __shfl_xor(sum, off);
    const float logp = logit - m - __logf(sum);

    const int y = labels[i];
    const float t = __shfl(logp, y);
    if (lane == 0) losses[k] = -t;
}

// ---------------------------------------------------------------------------
// Kernel D: mean of 1024 per-sample losses -> d_out[0].
// ---------------------------------------------------------------------------
__global__ __launch_bounds__(256) void k_reduce(
    const float* __restrict__ losses, float* __restrict__ out)
{
    __shared__ float sbuf[4];
    const int tid = threadIdx.x;
    float v = losses[tid] + losses[tid + 256] + losses[tid + 512] + losses[tid + 768];
#pragma unroll
    for (int off = 32; off; off >>= 1) v += __shfl_xor(v, off);
    if ((tid & 63) == 0) sbuf[tid >> 6] = v;
    __syncthreads();
    if (tid == 0) out[0] = (sbuf[0] + sbuf[1] + sbuf[2] + sbuf[3]) * (1.f / 1024.f);
}

// ---------------------------------------------------------------------------
extern "C" void kernel_launch(void* const* d_in, const int* in_sizes, int n_in,
                              void* d_out, int out_size, void* d_ws, size_t ws_size,
                              hipStream_t stream)
{
    const float* feat   = (const float*)d_in[0];
    const float* W      = (const float*)d_in[1];
    const float* av     = (const float*)d_in[2];
    const int*   adj1   = (const int*)d_in[3];
    const int*   adj2   = (const int*)d_in[4];
    const int*   labels = (const int*)d_in[5];
    const int*   idxt   = (const int*)d_in[6];

    const size_t MASKB = 2ull * NN * (NN / 32) * sizeof(unsigned);  // 16.78 MB
    const size_t HEAD  = (1u << 20) + (192u << 10);  // Vt2 1MB + sQ 128KB + dE 64KB

    auto needed = [&](size_t S, bool mask) -> size_t {
        return HEAD + (mask ? MASKB : 0)
             + 2 * S * NN * sizeof(float)
             + 2 * S * (size_t)NN * CDIM * sizeof(float)
             + NTRAIN * sizeof(float);
    };

    bool useMask = false;
    int scLog2 = 0;
    for (int s = 3; s >= 0; --s)
        if (ws_size >= needed((size_t)1 << s, true)) { useMask = true; scLog2 = s; break; }
    if (!useMask) {
        scLog2 = (ws_size >= needed(4, false)) ? 2
               : (ws_size >= needed(2, false)) ? 1 : 0;
    }
    const int SC = 1 << scLog2;

    char* ws = (char*)d_ws;
    unsigned short* Vt2 = (unsigned short*)ws;                 // 1 MB
    float4* sQ = (float4*)(ws + (1u << 20));                   // 128 KB
    float2* dEv = (float2*)(ws + (1u << 20) + (128u << 10));   // 64 KB
    char* p = ws + HEAD;
    unsigned* maskW = (unsigned*)p;
    if (useMask) p += MASKB;
    float* zP   = (float*)p;
    float* numP = (float*)(p + 2 * SC * NN * sizeof(float));
    float* losses = (float*)((char*)numP + 2 * (size_t)SC * NN * CDIM * sizeof(float));

    hipLaunchKernelGGL(k_wh, dim3(256), dim3(256), 0, stream,
                       feat, W, av, Vt2, sQ, dEv);
    if (useMask) {
        hipLaunchKernelGGL(k_pack, dim3(4096), dim3(256), 0, stream,
                           adj1, adj2, (unsigned short*)maskW);
        hipLaunchKernelGGL((k_attn<true>), dim3(256 * SC), dim3(256), 0, stream,
                           adj1, adj2, maskW, Vt2, sQ, dEv, numP, zP, scLog2);
    } else {
        hipLaunchKernelGGL((k_attn<false>), dim3(256 * SC), dim3(256), 0, stream,
                           adj1, adj2, maskW, Vt2, sQ, dEv, numP, zP, scLog2);
    }
    hipLaunchKernelGGL(k_loss, dim3(NTRAIN / 4), dim3(256), 0, stream,
                       numP, zP, labels, idxt, losses, SC);
    hipLaunchKernelGGL(k_reduce, dim3(1), dim3(256), 0, stream,
                       losses, (float*)d_out);
}

// Round 9
// 179.915 us; speedup vs baseline: 3.6883x; 1.4604x over previous
//
#include <hip/hip_runtime.h>
#include <hip/hip_bf16.h>

// GAT fused forward loss.
// R9 KEY INSIGHT: loss uses only h_all[idx_train] (1024 samples, ~960 distinct
// rows); GAT row i depends on adj[i,:] only -> unsampled rows are DEAD WORK.
// adj traffic: 537MB -> ~67MB (fits L3 -> warm replays are cache-served).
// Per (layer,sample) wave: p_j = exp(lrelu(s_i+d_j)) via factored exp
// (no transcendental), masked by adj row; out[c] = sum p_j Wh[j][c]; z = sum p.
// Two-phase per 1024-j chunk: build p (lane owns j%64==lane, coalesced) -> LDS,
// then accumulate (lane=c, p broadcast from LDS, Vt2f contiguous float4).
// relu(elu(x)) == relu(x); no softmax max-shift needed (|s+d| < ~8).

#define NN 8192
#define FTDIM 512
#define CDIM 64
#define NTRAIN 1024
#define LOG2E 1.44269504088896f

typedef __attribute__((ext_vector_type(8))) short short8;
typedef __attribute__((ext_vector_type(4))) float f32x4;
typedef __attribute__((ext_vector_type(4))) int i32x4;

// ---------------------------------------------------------------------------
// Kernel A: Wh = feat @ W (full -- all j needed as columns/d_j). Wave = 8 rows
// (one jblk), lane c owns column c. Writes Vt2f[jblk][c][8] f32 (reader gets
// contiguous 32B/lane, 2KB/wave per jblk) + factored-exp tables:
//   sQ[i] = (E1,E2,th) = (2^s', 2^(0.2 s'), 2^(-s'));  dE[j] = (2^d', 2^(0.2 d'))
// with s',d' log2e-scaled.  P = (e1>th ? E1*e1 : E2*e2) == exp(lrelu(s+d)).
// ---------------------------------------------------------------------------
__global__ __launch_bounds__(256) void k_wh(
    const float* __restrict__ feat, const float* __restrict__ W,
    const float* __restrict__ av, float* __restrict__ Vt2f,
    float4* __restrict__ sQ, float2* __restrict__ dE)
{
    const int lane = threadIdx.x & 63;
    const int wv   = (int)((blockIdx.x * blockDim.x + threadIdx.x) >> 6);
    const int row0 = wv * 8;
    const int c    = lane;

    float acc[8];
#pragma unroll
    for (int r = 0; r < 8; ++r) acc[r] = 0.f;

    for (int k = 0; k < FTDIM; k += 4) {
        f32x4 f[8];
#pragma unroll
        for (int r = 0; r < 8; ++r)
            f[r] = *(const f32x4*)(feat + (size_t)(row0 + r) * FTDIM + k);
#pragma unroll
        for (int kk = 0; kk < 4; ++kk) {
            float wval = W[(k + kk) * CDIM + c];
#pragma unroll
            for (int r = 0; r < 8; ++r)
                acc[r] = fmaf(f[r][kk], wval, acc[r]);
        }
    }

    // Vt2f[jblk=wv][c][0..8): two float4 stores, wave writes 2KB contiguous.
    float* vp = Vt2f + ((size_t)wv * 64 + c) * 8;
    *(float4*)(vp)     = make_float4(acc[0], acc[1], acc[2], acc[3]);
    *(float4*)(vp + 4) = make_float4(acc[4], acc[5], acc[6], acc[7]);

    const float a1 = av[c], a2 = av[CDIM + c];
#pragma unroll
    for (int r = 0; r < 8; ++r) {
        float s_ = acc[r] * a1;
        float d_ = acc[r] * a2;
#pragma unroll
        for (int off = 32; off; off >>= 1) {
            s_ += __shfl_xor(s_, off);
            d_ += __shfl_xor(d_, off);
        }
        if (lane == 0) {
            const float sp = s_ * LOG2E, dp_ = d_ * LOG2E;
            sQ[row0 + r] = make_float4(__builtin_amdgcn_exp2f(sp),
                                       __builtin_amdgcn_exp2f(0.2f * sp),
                                       __builtin_amdgcn_exp2f(-sp), 0.f);
            dE[row0 + r] = make_float2(__builtin_amdgcn_exp2f(dp_),
                                       __builtin_amdgcn_exp2f(0.2f * dp_));
        }
    }
}

// ---------------------------------------------------------------------------
// Kernel S: sampled-row attention aggregation. 2048 waves = 2 layers x 1024
// samples; wave owns one (l,k): row i = idxt[k]. Per 1024-j chunk (8 chunks):
//   build: lane computes p for j = j0 + m*64 + lane (m 0..15): coalesced adj
//          dword + dE float2, ~6 VALU; z accumulated per-lane; p -> LDS pbuf.
//   accum: lane = output column c: per 8-j group read p (2x f32x4 broadcast
//          from LDS) + Vt2f (2x float4 contiguous), 8 fma into acc.
// Outputs per sample slot k (duplicates independent -> no races, determinism).
// ---------------------------------------------------------------------------
__global__ __launch_bounds__(256) void k_sattn(
    const int* __restrict__ adj1, const int* __restrict__ adj2,
    const float* __restrict__ Vt2f, const float4* __restrict__ sQ,
    const float2* __restrict__ dE, const int* __restrict__ idxt,
    float* __restrict__ numO, float* __restrict__ zO)
{
    __shared__ float pbuf[4][1024];

    const int tid  = threadIdx.x;
    const int lane = tid & 63;
    const int wvb  = tid >> 6;
    const int w    = blockIdx.x * 4 + wvb;     // 0..2047
    const int l    = w >> 10;
    const int k    = w & 1023;
    const int i    = idxt[k];

    const int* __restrict__ arow = (l ? adj2 : adj1) + (size_t)i * NN;
    const float4 sq = sQ[i];
    const float E1 = sq.x, E2 = sq.y, th = sq.z;
    float* pb = pbuf[wvb];
    const int c = lane;
    const float* __restrict__ vbase = Vt2f + (size_t)c * 8;

    float accA = 0.f, accB = 0.f, z = 0.f;

    for (int ch = 0; ch < 8; ++ch) {
        const int j0 = ch * 1024;

        // ---- build phase: lane owns j = j0 + m*64 + lane ----
#pragma unroll
        for (int m = 0; m < 16; ++m) {
            const int j = j0 + m * 64 + lane;
            const int av = arow[j];
            const float2 de = dE[j];
            const bool pos = de.x > th;                 // <=> s'+d' > 0
            float p = (pos ? de.x : de.y) * (pos ? E1 : E2);
            p = (av != 0) ? p : 0.f;
            z += p;
            pb[m * 64 + lane] = p;
        }
        __syncthreads();   // pbuf visible (also orders vs next overwrite)

        // ---- accumulate phase: lane = column c ----
#pragma unroll 4
        for (int g = 0; g < 128; ++g) {
            const f32x4 p0 = *(const f32x4*)&pb[g * 8];
            const f32x4 p1 = *(const f32x4*)&pb[g * 8 + 4];
            const float* vp = vbase + ((size_t)(j0 >> 3) + g) * 512;
            const float4 v0 = *(const float4*)(vp);
            const float4 v1 = *(const float4*)(vp + 4);
            accA = fmaf(p0[0], v0.x, accA); accB = fmaf(p0[1], v0.y, accB);
            accA = fmaf(p0[2], v0.z, accA); accB = fmaf(p0[3], v0.w, accB);
            accA = fmaf(p1[0], v1.x, accA); accB = fmaf(p1[1], v1.y, accB);
            accA = fmaf(p1[2], v1.z, accA); accB = fmaf(p1[3], v1.w, accB);
        }
        __syncthreads();   // done reading pbuf before next build overwrites
    }

    // z: lane-partial sums -> full row sum (deterministic butterfly)
#pragma unroll
    for (int off = 32; off; off >>= 1) z += __shfl_xor(z, off);

    numO[((size_t)l * NTRAIN + k) * CDIM + c] = accA + accB;
    if (lane == 0) zO[l * NTRAIN + k] = z;
}

// ---------------------------------------------------------------------------
// Kernel C: per-sample loss. One wave per sample, lane = class.
// h = 0.5*(relu(n1/z1) + relu(n2/z2)); log-softmax over 64 lanes; NLL.
// ---------------------------------------------------------------------------
__global__ __launch_bounds__(256) void k_loss(
    const float* __restrict__ numO, const float* __restrict__ zO,
    const int* __restrict__ labels, const int* __restrict__ idxt,
    float* __restrict__ losses)
{
    const int lane = threadIdx.x & 63;
    const int k = (int)((blockIdx.x * blockDim.x + threadIdx.x) >> 6);
    const int i = idxt[k];

    const float n1 = numO[(size_t)k * CDIM + lane];
    const float n2 = numO[((size_t)NTRAIN + k) * CDIM + lane];
    const float z1 = zO[k];
    const float z2 = zO[NTRAIN + k];
    const float logit = 0.5f * (fmaxf(n1 / z1, 0.f) + fmaxf(n2 / z2, 0.f));

    float m = logit;
#pragma unroll
    for (int off = 32; off; off >>= 1) m = fmaxf(m, __shfl_xor(m, off));
    float ex = __expf(logit - m);
    float sum = ex;
#pragma unroll
    for (int off = 32; off; off >>= 1) sum += __shfl_xor(sum, off);
    const float logp = logit - m - __logf(sum);

    const int y = labels[i];
    const float t = __shfl(logp, y);
    if (lane == 0) losses[k] = -t;
}

// ---------------------------------------------------------------------------
// Kernel D: mean of 1024 per-sample losses -> d_out[0].
// ---------------------------------------------------------------------------
__global__ __launch_bounds__(256) void k_reduce(
    const float* __restrict__ losses, float* __restrict__ out)
{
    __shared__ float sbuf[4];
    const int tid = threadIdx.x;
    float v = losses[tid] + losses[tid + 256] + losses[tid + 512] + losses[tid + 768];
#pragma unroll
    for (int off = 32; off; off >>= 1) v += __shfl_xor(v, off);
    if ((tid & 63) == 0) sbuf[tid >> 6] = v;
    __syncthreads();
    if (tid == 0) out[0] = (sbuf[0] + sbuf[1] + sbuf[2] + sbuf[3]) * (1.f / 1024.f);
}

// ---------------------------------------------------------------------------
extern "C" void kernel_launch(void* const* d_in, const int* in_sizes, int n_in,
                              void* d_out, int out_size, void* d_ws, size_t ws_size,
                              hipStream_t stream)
{
    const float* feat   = (const float*)d_in[0];
    const float* W      = (const float*)d_in[1];
    const float* av     = (const float*)d_in[2];
    const int*   adj1   = (const int*)d_in[3];
    const int*   adj2   = (const int*)d_in[4];
    const int*   labels = (const int*)d_in[5];
    const int*   idxt   = (const int*)d_in[6];

    // ws layout (~2.8 MB total):
    char* ws = (char*)d_ws;
    float*  Vt2f = (float*)ws;                                   // 2 MB
    float4* sQ   = (float4*)(ws + (2u << 20));                   // 128 KB
    float2* dEv  = (float2*)(ws + (2u << 20) + (128u << 10));    // 64 KB
    float*  numO = (float*)(ws + (2u << 20) + (192u << 10));     // 512 KB
    float*  zO   = numO + 2ull * NTRAIN * CDIM;                  // 8 KB
    float*  losses = zO + 2 * NTRAIN;                            // 4 KB

    hipLaunchKernelGGL(k_wh, dim3(256), dim3(256), 0, stream,
                       feat, W, av, Vt2f, sQ, dEv);
    hipLaunchKernelGGL(k_sattn, dim3(512), dim3(256), 0, stream,
                       adj1, adj2, Vt2f, sQ, dEv, idxt, numO, zO);
    hipLaunchKernelGGL(k_loss, dim3(NTRAIN / 4), dim3(256), 0, stream,
                       numO, zO, labels, idxt, losses);
    hipLaunchKernelGGL(k_reduce, dim3(1), dim3(256), 0, stream,
                       losses, (float*)d_out);
}

// Round 10
// 95.866 us; speedup vs baseline: 6.9219x; 1.8767x over previous
//
#include <hip/hip_runtime.h>
#include <hip/hip_bf16.h>

// GAT fused forward loss.
// R10: only h_all[idx_train] is live (R9 insight) + MFMA j-amortization over
// 16 samples/wave (R9's k_sattn read Vt2 per-sample => 4.3GB L2 traffic; now
// Vt2 read once per 16 samples => 134MB). Wave owns (layer, 16 samples,
// j-chunk); per 32-j tile the A-frag p = adj ? exp(lrelu(s+d)) : 0 is built
// IN REGISTERS (adj row i32x4 + dE f32x4 + factored exp, no transcendental,
// no LDS, no barriers); 4 MFMAs numerator + 1 MFMA vs ones = Z.
// relu(elu(x)) == relu(x); no softmax max-shift needed (|s+d| < ~8).

#define NN 8192
#define FTDIM 512
#define CDIM 64
#define NTRAIN 1024
#define LOG2E 1.44269504088896f

typedef __attribute__((ext_vector_type(8))) short short8;
typedef __attribute__((ext_vector_type(4))) float f32x4;
typedef __attribute__((ext_vector_type(4))) int i32x4;

static __device__ __forceinline__ unsigned short f2bf(float x) {
    return __bfloat16_as_ushort(__float2bfloat16(x));
}

// ---------------------------------------------------------------------------
// Kernel A: Wh = feat @ W. 2 rows/wave (4096 waves -> 16/CU for latency
// hiding). Lane c owns column c. Writes Vt2[jblk][c][e]=bf16(Wh[jblk*8+e][c])
// (ushort2 per lane, rows paired) + factored-exp tables:
//   sQ[i] = (E1,E2,th) = (2^s', 2^(0.2 s'), 2^(-s')); dE[j] = (2^d',2^(0.2 d'))
// (s',d' log2e-scaled). P = (e1>th ? E1*e1 : E2*e2) == exp(lrelu(s+d)).
// ---------------------------------------------------------------------------
__global__ __launch_bounds__(256) void k_wh(
    const float* __restrict__ feat, const float* __restrict__ W,
    const float* __restrict__ av, unsigned short* __restrict__ Vt2,
    float4* __restrict__ sQ, float2* __restrict__ dE)
{
    const int lane = threadIdx.x & 63;
    const int wv   = (int)((blockIdx.x * blockDim.x + threadIdx.x) >> 6);
    const int row0 = wv * 2;
    const int c    = lane;

    float acc0 = 0.f, acc1 = 0.f;

    for (int k = 0; k < FTDIM; k += 4) {
        f32x4 f0 = *(const f32x4*)(feat + (size_t)row0 * FTDIM + k);
        f32x4 f1 = *(const f32x4*)(feat + (size_t)(row0 + 1) * FTDIM + k);
#pragma unroll
        for (int kk = 0; kk < 4; ++kk) {
            const float wval = W[(k + kk) * CDIM + c];
            acc0 = fmaf(f0[kk], wval, acc0);
            acc1 = fmaf(f1[kk], wval, acc1);
        }
    }

    // Vt2[jblk][c][8]: rows row0,row0+1 are elements (row0&7, +1) -> ushort2
    *(ushort2*)(Vt2 + (size_t)(row0 >> 3) * 512 + c * 8 + (row0 & 7)) =
        make_ushort2(f2bf(acc0), f2bf(acc1));

    const float a1 = av[c], a2 = av[CDIM + c];
#pragma unroll
    for (int r = 0; r < 2; ++r) {
        const float a = r ? acc1 : acc0;
        float s_ = a * a1;
        float d_ = a * a2;
#pragma unroll
        for (int off = 32; off; off >>= 1) {
            s_ += __shfl_xor(s_, off);
            d_ += __shfl_xor(d_, off);
        }
        if (lane == 0) {
            const float sp = s_ * LOG2E, dp_ = d_ * LOG2E;
            sQ[row0 + r] = make_float4(__builtin_amdgcn_exp2f(sp),
                                       __builtin_amdgcn_exp2f(0.2f * sp),
                                       __builtin_amdgcn_exp2f(-sp), 0.f);
            dE[row0 + r] = make_float2(__builtin_amdgcn_exp2f(dp_),
                                       __builtin_amdgcn_exp2f(0.2f * dp_));
        }
    }
}

// ---------------------------------------------------------------------------
// Kernel M: sampled-row masked-softmax aggregation via MFMA.
// Wave = (layer l, sample-block sb of 16, j-chunk sc of SC). 2*64*SC waves.
// Lane (r,kg): sample row = idxt[sb*16+r]; per 32-j tile builds A-frag
// elements p(sample r, j = j0+jt*32+kg*8+e) in registers:
//   2x i32x4 adj (sampled row, 32B/lane), 4x f32x4 dE (L1 broadcast),
//   p = bit ? (e1>th ? E1*e1 : E2*e2) : 0, bf16.
// B-frags: 4x short8 from Vt2 (L2; read once per 16 samples => 16x less
// traffic than R9). 4 MFMAs numerator + 1 vs ones = Z.
// Partials per (l,sc) slot summed in k_loss (deterministic, no atomics).
// ---------------------------------------------------------------------------
__global__ __launch_bounds__(256, 4) void k_mattn(
    const int* __restrict__ adj1, const int* __restrict__ adj2,
    const unsigned short* __restrict__ Vt2, const float4* __restrict__ sQ,
    const float2* __restrict__ dE, const int* __restrict__ idxt,
    float* __restrict__ numPart, float* __restrict__ zPart, const int scLog2)
{
    const int lane = threadIdx.x & 63;
    const int w = (int)((blockIdx.x * blockDim.x + threadIdx.x) >> 6);
    const int l   = w >> (6 + scLog2);
    const int rem = w & ((64 << scLog2) - 1);
    const int sb  = rem >> scLog2;
    const int sc  = rem & ((1 << scLog2) - 1);

    const int r  = lane & 15;
    const int kg = lane >> 4;

    const int i = idxt[sb * 16 + r];
    const float4 sq = sQ[i];
    const float E1 = sq.x, E2 = sq.y, th = sq.z;

    const int jchunk = NN >> scLog2;
    const int j0 = sc * jchunk;
    const int ntiles = jchunk >> 5;

    const int* __restrict__ arow = (l ? adj2 : adj1) + (size_t)i * NN + j0 + kg * 8;
    const float* __restrict__ dEf = (const float*)dE;

    short8 bOnes;
#pragma unroll
    for (int e = 0; e < 8; ++e) bOnes[e] = (short)0x3F80;   // bf16 1.0

    f32x4 acc0 = {0.f, 0.f, 0.f, 0.f};
    f32x4 acc1 = acc0, acc2 = acc0, acc3 = acc0, accz = acc0;

    for (int jt = 0; jt < ntiles; ++jt) {
        const int jrel = jt * 32;
        const i32x4 m0 = *(const i32x4*)(arow + jrel);
        const i32x4 m1 = *(const i32x4*)(arow + jrel + 4);
        const f32x4* dp = (const f32x4*)(dEf + 2 * ((size_t)j0 + jrel + kg * 8));
        const f32x4 q0 = dp[0], q1 = dp[1], q2 = dp[2], q3 = dp[3];
        const unsigned short* vp =
            Vt2 + (((size_t)(j0 + jrel + kg * 8)) >> 3 << 9) + (r << 3);
        const short8 b0 = *(const short8*)(vp);
        const short8 b1 = *(const short8*)(vp + 128);
        const short8 b2 = *(const short8*)(vp + 256);
        const short8 b3 = *(const short8*)(vp + 384);

        short8 af;
#pragma unroll
        for (int e = 0; e < 8; ++e) {
            float e1, e2;
            switch (e >> 1) {
                case 0: e1 = q0[(e&1)*2]; e2 = q0[(e&1)*2+1]; break;
                case 1: e1 = q1[(e&1)*2]; e2 = q1[(e&1)*2+1]; break;
                case 2: e1 = q2[(e&1)*2]; e2 = q2[(e&1)*2+1]; break;
                default: e1 = q3[(e&1)*2]; e2 = q3[(e&1)*2+1]; break;
            }
            const bool pos = e1 > th;                 // <=> s'+d' > 0
            float p = (pos ? e1 : e2) * (pos ? E1 : E2);
            const bool on = (e < 4 ? m0[e] : m1[e - 4]) != 0;
            p = on ? p : 0.f;
            af[e] = (short)f2bf(p);
        }

        acc0 = __builtin_amdgcn_mfma_f32_16x16x32_bf16(af, b0, acc0, 0, 0, 0);
        acc1 = __builtin_amdgcn_mfma_f32_16x16x32_bf16(af, b1, acc1, 0, 0, 0);
        acc2 = __builtin_amdgcn_mfma_f32_16x16x32_bf16(af, b2, acc2, 0, 0, 0);
        acc3 = __builtin_amdgcn_mfma_f32_16x16x32_bf16(af, b3, acc3, 0, 0, 0);
        accz = __builtin_amdgcn_mfma_f32_16x16x32_bf16(af, bOnes, accz, 0, 0, 0);
    }

    // C/D layout: col = lane&15 (=r), row = kg*4+q (= sample within block)
    const size_t base = ((size_t)(l << scLog2) + sc) * NTRAIN + sb * 16;
    if (r == 0) {
#pragma unroll
        for (int q = 0; q < 4; ++q) zPart[base + kg * 4 + q] = accz[q];
    }
#pragma unroll
    for (int q = 0; q < 4; ++q) {
        float* op = numPart + (base + kg * 4 + q) * CDIM + r;
        op[0]  = acc0[q];
        op[16] = acc1[q];
        op[32] = acc2[q];
        op[48] = acc3[q];
    }
}

// ---------------------------------------------------------------------------
// Kernel C: per-sample loss. One wave per sample, lane = class. Sums the SC
// j-chunk partials, then h = 0.5*(relu(n1/z1)+relu(n2/z2)); log-softmax; NLL.
// ---------------------------------------------------------------------------
__global__ __launch_bounds__(256) void k_loss(
    const float* __restrict__ numPart, const float* __restrict__ zPart,
    const int* __restrict__ labels, const int* __restrict__ idxt,
    float* __restrict__ losses, const int scLog2)
{
    const int lane = threadIdx.x & 63;
    const int k = (int)((blockIdx.x * blockDim.x + threadIdx.x) >> 6);
    const int SC = 1 << scLog2;

    float logit = 0.f;
#pragma unroll
    for (int l = 0; l < 2; ++l) {
        float nsum = 0.f, zsum = 0.f;
        for (int s = 0; s < SC; ++s) {
            const size_t row = (size_t)(l * SC + s) * NTRAIN + k;
            nsum += numPart[row * CDIM + lane];
            zsum += zPart[row];
        }
        logit += fmaxf(nsum / zsum, 0.f);   // relu(elu(x)) == relu(x)
    }
    logit *= 0.5f;

    float m = logit;
#pragma unroll
    for (int off = 32; off; off >>= 1) m = fmaxf(m, __shfl_xor(m, off));
    float ex = __expf(logit - m);
    float sum = ex;
#pragma unroll
    for (int off = 32; off; off >>= 1) sum += __shfl_xor(sum, off);
    const float logp = logit - m - __logf(sum);

    const int y = labels[idxt[k]];
    const float t = __shfl(logp, y);
    if (lane == 0) losses[k] = -t;
}

// ---------------------------------------------------------------------------
// Kernel D: mean of 1024 per-sample losses -> d_out[0].
// ---------------------------------------------------------------------------
__global__ __launch_bounds__(256) void k_reduce(
    const float* __restrict__ losses, float* __restrict__ out)
{
    __shared__ float sbuf[4];
    const int tid = threadIdx.x;
    float v = losses[tid] + losses[tid + 256] + losses[tid + 512] + losses[tid + 768];
#pragma unroll
    for (int off = 32; off; off >>= 1) v += __shfl_xor(v, off);
    if ((tid & 63) == 0) sbuf[tid >> 6] = v;
    __syncthreads();
    if (tid == 0) out[0] = (sbuf[0] + sbuf[1] + sbuf[2] + sbuf[3]) * (1.f / 1024.f);
}

// ---------------------------------------------------------------------------
extern "C" void kernel_launch(void* const* d_in, const int* in_sizes, int n_in,
                              void* d_out, int out_size, void* d_ws, size_t ws_size,
                              hipStream_t stream)
{
    const float* feat   = (const float*)d_in[0];
    const float* W      = (const float*)d_in[1];
    const float* av     = (const float*)d_in[2];
    const int*   adj1   = (const int*)d_in[3];
    const int*   adj2   = (const int*)d_in[4];
    const int*   labels = (const int*)d_in[5];
    const int*   idxt   = (const int*)d_in[6];

    const size_t HEAD = (1u << 20) + (192u << 10);   // Vt2 1MB + sQ 128KB + dE 64KB

    auto needed = [&](int scl) -> size_t {
        const size_t SC = (size_t)1 << scl;
        return HEAD + 2 * SC * NTRAIN * CDIM * sizeof(float)   // numPart
                    + 2 * SC * NTRAIN * sizeof(float)          // zPart
                    + NTRAIN * sizeof(float);                  // losses
    };
    int scLog2 = 3;
    for (int s = 5; s >= 3; --s)
        if (ws_size >= needed(s)) { scLog2 = s; break; }
    const int SC = 1 << scLog2;

    char* ws = (char*)d_ws;
    unsigned short* Vt2 = (unsigned short*)ws;                  // 1 MB
    float4* sQ  = (float4*)(ws + (1u << 20));                   // 128 KB
    float2* dEv = (float2*)(ws + (1u << 20) + (128u << 10));    // 64 KB
    float*  numPart = (float*)(ws + HEAD);
    float*  zPart   = numPart + 2ull * SC * NTRAIN * CDIM;
    float*  losses  = zPart + 2ull * SC * NTRAIN;

    hipLaunchKernelGGL(k_wh, dim3(1024), dim3(256), 0, stream,
                       feat, W, av, Vt2, sQ, dEv);
    // 2 * 64 * SC waves = 32*SC blocks of 4 waves
    hipLaunchKernelGGL(k_mattn, dim3(32 * SC), dim3(256), 0, stream,
                       adj1, adj2, Vt2, sQ, dEv, idxt, numPart, zPart, scLog2);
    hipLaunchKernelGGL(k_loss, dim3(NTRAIN / 4), dim3(256), 0, stream,
                       numPart, zPart, labels, idxt, losses, scLog2);
    hipLaunchKernelGGL(k_reduce, dim3(1), dim3(256), 0, stream,
                       losses, (float*)d_out);
}

// Round 11
// 79.644 us; speedup vs baseline: 8.3318x; 1.2037x over previous
//
#include <hip/hip_runtime.h>
#include <hip/hip_bf16.h>

// GAT fused forward loss.
// R11: R10 structure (sampled rows + MFMA j-amortization) with latency fixes:
//  - k_mattn: 2-deep software pipeline (tile jt+1 loads issued before
//    computing jt -> 2x memory-level parallelism; kernel is latency-bound,
//    10 gather loads/tile), dE split SoA (dE1=2^d', dE2=2^(0.2d')).
//  - partials relaid [sample][layer][chunk][c] -> k_loss reads contiguous
//    16KB/sample instead of 256KB-strided gathers.
// relu(elu(x)) == relu(x); no softmax max-shift needed (|s+d| < ~8).

#define NN 8192
#define FTDIM 512
#define CDIM 64
#define NTRAIN 1024
#define LOG2E 1.44269504088896f

typedef __attribute__((ext_vector_type(8))) short short8;
typedef __attribute__((ext_vector_type(4))) float f32x4;
typedef __attribute__((ext_vector_type(4))) int i32x4;

static __device__ __forceinline__ unsigned short f2bf(float x) {
    return __bfloat16_as_ushort(__float2bfloat16(x));
}

// ---------------------------------------------------------------------------
// Kernel A: Wh = feat @ W. 2 rows/wave (4096 waves). Lane c owns column c.
// Writes Vt2[jblk][c][e]=bf16(Wh[jblk*8+e][c]) + factored-exp tables:
//   sQ[i] = (E1,E2,th) = (2^s', 2^(0.2 s'), 2^(-s'))
//   dE1[j] = 2^d', dE2[j] = 2^(0.2 d')          (s',d' log2e-scaled)
// P = (e1>th ? E1*e1 : E2*e2) == exp(lrelu(s+d)) exactly.
// ---------------------------------------------------------------------------
__global__ __launch_bounds__(256) void k_wh(
    const float* __restrict__ feat, const float* __restrict__ W,
    const float* __restrict__ av, unsigned short* __restrict__ Vt2,
    float4* __restrict__ sQ, float* __restrict__ dE1, float* __restrict__ dE2)
{
    const int lane = threadIdx.x & 63;
    const int wv   = (int)((blockIdx.x * blockDim.x + threadIdx.x) >> 6);
    const int row0 = wv * 2;
    const int c    = lane;

    float acc0 = 0.f, acc1 = 0.f;

    for (int k = 0; k < FTDIM; k += 4) {
        f32x4 f0 = *(const f32x4*)(feat + (size_t)row0 * FTDIM + k);
        f32x4 f1 = *(const f32x4*)(feat + (size_t)(row0 + 1) * FTDIM + k);
#pragma unroll
        for (int kk = 0; kk < 4; ++kk) {
            const float wval = W[(k + kk) * CDIM + c];
            acc0 = fmaf(f0[kk], wval, acc0);
            acc1 = fmaf(f1[kk], wval, acc1);
        }
    }

    *(ushort2*)(Vt2 + (size_t)(row0 >> 3) * 512 + c * 8 + (row0 & 7)) =
        make_ushort2(f2bf(acc0), f2bf(acc1));

    const float a1 = av[c], a2 = av[CDIM + c];
#pragma unroll
    for (int r = 0; r < 2; ++r) {
        const float a = r ? acc1 : acc0;
        float s_ = a * a1;
        float d_ = a * a2;
#pragma unroll
        for (int off = 32; off; off >>= 1) {
            s_ += __shfl_xor(s_, off);
            d_ += __shfl_xor(d_, off);
        }
        if (lane == 0) {
            const float sp = s_ * LOG2E, dp_ = d_ * LOG2E;
            sQ[row0 + r] = make_float4(__builtin_amdgcn_exp2f(sp),
                                       __builtin_amdgcn_exp2f(0.2f * sp),
                                       __builtin_amdgcn_exp2f(-sp), 0.f);
            dE1[row0 + r] = __builtin_amdgcn_exp2f(dp_);
            dE2[row0 + r] = __builtin_amdgcn_exp2f(0.2f * dp_);
        }
    }
}

// ---------------------------------------------------------------------------
// Kernel M: sampled-row masked-softmax aggregation via MFMA, 2-deep pipeline.
// Wave = (layer l, sample-block sb of 16, j-chunk sc of SC). Lane (r,kg):
// sample row i = idxt[sb*16+r]. Per 32-j tile (10 loads, all issued one tile
// ahead): adj 2x i32x4 (row gather), dE1/dE2 4x f32x4, Vt2 4x short8;
// p = bit ? (e1>th ? E1*e1 : E2*e2) : 0 -> bf16 A-frag; 4 MFMAs numerator +
// 1 vs ones = Z. Partials laid [sample][layer][chunk][c] (k_loss-friendly).
// ---------------------------------------------------------------------------
struct TileT {
    i32x4 m0, m1;
    f32x4 a0, a1, b0, b1;
    short8 v0, v1, v2, v3;
};

__global__ __launch_bounds__(256, 4) void k_mattn(
    const int* __restrict__ adj1, const int* __restrict__ adj2,
    const unsigned short* __restrict__ Vt2, const float4* __restrict__ sQ,
    const float* __restrict__ dE1, const float* __restrict__ dE2,
    const int* __restrict__ idxt,
    float* __restrict__ numPart, float* __restrict__ zPart, const int scLog2)
{
    const int lane = threadIdx.x & 63;
    const int w = (int)((blockIdx.x * blockDim.x + threadIdx.x) >> 6);
    const int l   = w >> (6 + scLog2);
    const int rem = w & ((64 << scLog2) - 1);
    const int sb  = rem >> scLog2;
    const int sc  = rem & ((1 << scLog2) - 1);

    const int r  = lane & 15;
    const int kg = lane >> 4;

    const int i = idxt[sb * 16 + r];
    const float4 sq = sQ[i];
    const float E1 = sq.x, E2 = sq.y, th = sq.z;

    const int jchunk = NN >> scLog2;
    const int j0 = sc * jchunk;
    const int ntiles = jchunk >> 5;          // 8 at SC=32 (even)

    const int* __restrict__ arow = (l ? adj2 : adj1) + (size_t)i * NN + j0 + kg * 8;
    const float* __restrict__ d1p = dE1 + j0 + kg * 8;
    const float* __restrict__ d2p = dE2 + j0 + kg * 8;
    const unsigned short* __restrict__ vbase =
        Vt2 + (((size_t)j0 >> 3) << 9) + ((size_t)kg << 9) + (r << 3);

    short8 bOnes;
#pragma unroll
    for (int e = 0; e < 8; ++e) bOnes[e] = (short)0x3F80;   // bf16 1.0

    f32x4 acc0 = {0.f, 0.f, 0.f, 0.f};
    f32x4 acc1 = acc0, acc2 = acc0, acc3 = acc0, accz = acc0;

    TileT tA, tB;

#define LOADT(T, JT) do { const int _jr = (JT) * 32;                           \
    T.m0 = *(const i32x4*)(arow + _jr);                                        \
    T.m1 = *(const i32x4*)(arow + _jr + 4);                                    \
    T.a0 = *(const f32x4*)(d1p + _jr);                                         \
    T.a1 = *(const f32x4*)(d1p + _jr + 4);                                     \
    T.b0 = *(const f32x4*)(d2p + _jr);                                         \
    T.b1 = *(const f32x4*)(d2p + _jr + 4);                                     \
    const unsigned short* _vp = vbase + ((size_t)(JT) << 11);                  \
    T.v0 = *(const short8*)(_vp);                                              \
    T.v1 = *(const short8*)(_vp + 128);                                        \
    T.v2 = *(const short8*)(_vp + 256);                                        \
    T.v3 = *(const short8*)(_vp + 384);                                        \
} while (0)

#define COMPT(T) do {                                                          \
    short8 af;                                                                 \
    _Pragma("unroll")                                                          \
    for (int e = 0; e < 8; ++e) {                                              \
        const float e1 = (e < 4) ? T.a0[e & 3] : T.a1[e & 3];                  \
        const float e2 = (e < 4) ? T.b0[e & 3] : T.b1[e & 3];                  \
        const bool pos = e1 > th;                                              \
        float p = (pos ? e1 : e2) * (pos ? E1 : E2);                           \
        const bool on = ((e < 4) ? T.m0[e & 3] : T.m1[e & 3]) != 0;            \
        p = on ? p : 0.f;                                                      \
        af[e] = (short)f2bf(p);                                                \
    }                                                                          \
    acc0 = __builtin_amdgcn_mfma_f32_16x16x32_bf16(af, T.v0, acc0, 0, 0, 0);   \
    acc1 = __builtin_amdgcn_mfma_f32_16x16x32_bf16(af, T.v1, acc1, 0, 0, 0);   \
    acc2 = __builtin_amdgcn_mfma_f32_16x16x32_bf16(af, T.v2, acc2, 0, 0, 0);   \
    acc3 = __builtin_amdgcn_mfma_f32_16x16x32_bf16(af, T.v3, acc3, 0, 0, 0);   \
    accz = __builtin_amdgcn_mfma_f32_16x16x32_bf16(af, bOnes, accz, 0, 0, 0);  \
} while (0)

    LOADT(tA, 0);
    for (int jt = 0; jt < ntiles - 2; jt += 2) {
        LOADT(tB, jt + 1);
        COMPT(tA);
        LOADT(tA, jt + 2);
        COMPT(tB);
    }
    LOADT(tB, ntiles - 1);
    COMPT(tA);
    COMPT(tB);
#undef LOADT
#undef COMPT

    // D layout: n-col = r (class), m-row = kg*4+q (sample within block).
    const int SC = 1 << scLog2;
#pragma unroll
    for (int q = 0; q < 4; ++q) {
        const int ks = sb * 16 + kg * 4 + q;
        const size_t slot = ((size_t)ks * 2 + l) * SC + sc;
        float* op = numPart + slot * CDIM + r;
        op[0]  = acc0[q];
        op[16] = acc1[q];
        op[32] = acc2[q];
        op[48] = acc3[q];
        if (r == 0) zPart[slot] = accz[q];
    }
}

// ---------------------------------------------------------------------------
// Kernel C: per-sample loss. One wave per sample k, lane = class. Partials
// for (k,l) are contiguous (SC*64 floats): lane sums SC strided-256B floats;
// z via lane-parallel load + butterfly. Then h = 0.5*(relu(n1/z1)+relu(n2/z2)),
// log-softmax over 64 lanes, NLL.
// ---------------------------------------------------------------------------
__global__ __launch_bounds__(256) void k_loss(
    const float* __restrict__ numPart, const float* __restrict__ zPart,
    const int* __restrict__ labels, const int* __restrict__ idxt,
    float* __restrict__ losses, const int scLog2)
{
    const int lane = threadIdx.x & 63;
    const int k = (int)((blockIdx.x * blockDim.x + threadIdx.x) >> 6);
    const int SC = 1 << scLog2;

    float logit = 0.f;
#pragma unroll
    for (int l = 0; l < 2; ++l) {
        const size_t base = ((size_t)k * 2 + l) * SC;
        float ns = 0.f;
#pragma unroll 8
        for (int s = 0; s < SC; ++s)
            ns += numPart[(base + s) * CDIM + lane];
        float zs = (lane < SC) ? zPart[base + lane] : 0.f;
#pragma unroll
        for (int off = 32; off; off >>= 1) zs += __shfl_xor(zs, off);
        logit += fmaxf(ns / zs, 0.f);   // relu(elu(x)) == relu(x)
    }
    logit *= 0.5f;

    float m = logit;
#pragma unroll
    for (int off = 32; off; off >>= 1) m = fmaxf(m, __shfl_xor(m, off));
    float ex = __expf(logit - m);
    float sum = ex;
#pragma unroll
    for (int off = 32; off; off >>= 1) sum += __shfl_xor(sum, off);
    const float logp = logit - m - __logf(sum);

    const int y = labels[idxt[k]];
    const float t = __shfl(logp, y);
    if (lane == 0) losses[k] = -t;
}

// ---------------------------------------------------------------------------
// Kernel D: mean of 1024 per-sample losses -> d_out[0].
// ---------------------------------------------------------------------------
__global__ __launch_bounds__(256) void k_reduce(
    const float* __restrict__ losses, float* __restrict__ out)
{
    __shared__ float sbuf[4];
    const int tid = threadIdx.x;
    float v = losses[tid] + losses[tid + 256] + losses[tid + 512] + losses[tid + 768];
#pragma unroll
    for (int off = 32; off; off >>= 1) v += __shfl_xor(v, off);
    if ((tid & 63) == 0) sbuf[tid >> 6] = v;
    __syncthreads();
    if (tid == 0) out[0] = (sbuf[0] + sbuf[1] + sbuf[2] + sbuf[3]) * (1.f / 1024.f);
}

// ---------------------------------------------------------------------------
extern "C" void kernel_launch(void* const* d_in, const int* in_sizes, int n_in,
                              void* d_out, int out_size, void* d_ws, size_t ws_size,
                              hipStream_t stream)
{
    const float* feat   = (const float*)d_in[0];
    const float* W      = (const float*)d_in[1];
    const float* av     = (const float*)d_in[2];
    const int*   adj1   = (const int*)d_in[3];
    const int*   adj2   = (const int*)d_in[4];
    const int*   labels = (const int*)d_in[5];
    const int*   idxt   = (const int*)d_in[6];

    const size_t HEAD = (1u << 20) + (192u << 10);  // Vt2 1MB + sQ 128KB + dE1/2 64KB

    auto needed = [&](int scl) -> size_t {
        const size_t SC = (size_t)1 << scl;
        return HEAD + 2 * SC * NTRAIN * CDIM * sizeof(float)
                    + 2 * SC * NTRAIN * sizeof(float)
                    + NTRAIN * sizeof(float);
    };
    int scLog2 = 3;
    for (int s = 5; s >= 3; --s)
        if (ws_size >= needed(s)) { scLog2 = s; break; }
    const int SC = 1 << scLog2;

    char* ws = (char*)d_ws;
    unsigned short* Vt2 = (unsigned short*)ws;                  // 1 MB
    float4* sQ  = (float4*)(ws + (1u << 20));                   // 128 KB
    float*  dE1 = (float*)(ws + (1u << 20) + (128u << 10));     // 32 KB
    float*  dE2 = (float*)(ws + (1u << 20) + (160u << 10));     // 32 KB
    float*  numPart = (float*)(ws + HEAD);
    float*  zPart   = numPart + 2ull * SC * NTRAIN * CDIM;
    float*  losses  = zPart + 2ull * SC * NTRAIN;

    hipLaunchKernelGGL(k_wh, dim3(1024), dim3(256), 0, stream,
                       feat, W, av, Vt2, sQ, dE1, dE2);
    hipLaunchKernelGGL(k_mattn, dim3(32 * SC), dim3(256), 0, stream,
                       adj1, adj2, Vt2, sQ, dE1, dE2, idxt, numPart, zPart, scLog2);
    hipLaunchKernelGGL(k_loss, dim3(NTRAIN / 4), dim3(256), 0, stream,
                       numPart, zPart, labels, idxt, losses, scLog2);
    hipLaunchKernelGGL(k_reduce, dim3(1), dim3(256), 0, stream,
                       losses, (float*)d_out);
}

// Round 12
// 72.137 us; speedup vs baseline: 9.1988x; 1.1041x over previous
//
#include <hip/hip_runtime.h>
#include <hip/hip_bf16.h>

// GAT fused forward loss.
// R12: R11 structure (sampled rows + MFMA j-amortization over 16 samples).
// k_mattn v3: the adj stream is the only cold stream (read-once per call) and
// an 8-iter 2-deep pipeline left ~420cyc/tile exposed => preload ALL of the
// wave's adj tiles up front (16 i32x4 issued back-to-back), compress to 8-bit
// masks (frees the 64 VGPRs), then run the dE/Vt2 (L2-hot) loop 2-deep.
// k_wh back to 8 rows/wave (W L2 traffic 537->134MB).
// relu(elu(x)) == relu(x); no softmax max-shift needed (|s+d| < ~8).

#define NN 8192
#define FTDIM 512
#define CDIM 64
#define NTRAIN 1024
#define LOG2E 1.44269504088896f

typedef __attribute__((ext_vector_type(8))) short short8;
typedef __attribute__((ext_vector_type(4))) float f32x4;
typedef __attribute__((ext_vector_type(4))) int i32x4;

static __device__ __forceinline__ unsigned short f2bf(float x) {
    return __bfloat16_as_ushort(__float2bfloat16(x));
}

// ---------------------------------------------------------------------------
// Kernel A: Wh = feat @ W. 8 rows/wave (1024 waves; W read once per wave =
// 134MB L2). Lane c owns column c. Writes Vt2[jblk][c][e]=bf16(Wh[jblk*8+e][c])
// + factored-exp tables: sQ[i]=(2^s', 2^(0.2s'), 2^(-s')); dE1=2^d', dE2=2^(0.2d')
// (s',d' log2e-scaled). P = (e1>th ? E1*e1 : E2*e2) == exp(lrelu(s+d)).
// ---------------------------------------------------------------------------
__global__ __launch_bounds__(256) void k_wh(
    const float* __restrict__ feat, const float* __restrict__ W,
    const float* __restrict__ av, unsigned short* __restrict__ Vt2,
    float4* __restrict__ sQ, float* __restrict__ dE1, float* __restrict__ dE2)
{
    const int lane = threadIdx.x & 63;
    const int wv   = (int)((blockIdx.x * blockDim.x + threadIdx.x) >> 6);
    const int row0 = wv * 8;
    const int c    = lane;

    float acc[8];
#pragma unroll
    for (int r = 0; r < 8; ++r) acc[r] = 0.f;

    for (int k = 0; k < FTDIM; k += 4) {
        f32x4 f[8];
#pragma unroll
        for (int r = 0; r < 8; ++r)
            f[r] = *(const f32x4*)(feat + (size_t)(row0 + r) * FTDIM + k);
#pragma unroll
        for (int kk = 0; kk < 4; ++kk) {
            const float wval = W[(k + kk) * CDIM + c];
#pragma unroll
            for (int r = 0; r < 8; ++r)
                acc[r] = fmaf(f[r][kk], wval, acc[r]);
        }
    }

    short8 v;
#pragma unroll
    for (int r = 0; r < 8; ++r) v[r] = (short)f2bf(acc[r]);
    *(short8*)(Vt2 + (size_t)wv * 512 + c * 8) = v;   // [jblk][c][8]

    const float a1 = av[c], a2 = av[CDIM + c];
#pragma unroll
    for (int r = 0; r < 8; ++r) {
        float s_ = acc[r] * a1;
        float d_ = acc[r] * a2;
#pragma unroll
        for (int off = 32; off; off >>= 1) {
            s_ += __shfl_xor(s_, off);
            d_ += __shfl_xor(d_, off);
        }
        if (lane == 0) {
            const float sp = s_ * LOG2E, dp_ = d_ * LOG2E;
            sQ[row0 + r] = make_float4(__builtin_amdgcn_exp2f(sp),
                                       __builtin_amdgcn_exp2f(0.2f * sp),
                                       __builtin_amdgcn_exp2f(-sp), 0.f);
            dE1[row0 + r] = __builtin_amdgcn_exp2f(dp_);
            dE2[row0 + r] = __builtin_amdgcn_exp2f(0.2f * dp_);
        }
    }
}

// ---------------------------------------------------------------------------
// Kernel M v3 (template on SCL): wave = (layer l, sample-block sb, chunk sc).
// Prologue: ALL NT tiles' adj loads issued back-to-back (cold stream, paid
// once), compressed to mbits[NT] (bit e of tile t = adj!=0). Main loop:
// 2-deep pipeline over dE1/dE2 (L1/L2 broadcast) + Vt2 (L2-hot);
// p = bit ? (e1>th ? E1*e1 : E2*e2) : 0 -> bf16 A-frag; 4 MFMAs + 1 vs ones.
// Partials [sample][layer][chunk][c].
// ---------------------------------------------------------------------------
struct TileS {
    f32x4 a0, a1, b0, b1;
    short8 v0, v1, v2, v3;
};

template<int SCL>
__global__ __launch_bounds__(256, 4) void k_mattn(
    const int* __restrict__ adj1, const int* __restrict__ adj2,
    const unsigned short* __restrict__ Vt2, const float4* __restrict__ sQ,
    const float* __restrict__ dE1, const float* __restrict__ dE2,
    const int* __restrict__ idxt,
    float* __restrict__ numPart, float* __restrict__ zPart)
{
    constexpr int NT = (NN >> SCL) >> 5;     // tiles per wave
    const int lane = threadIdx.x & 63;
    const int w = (int)((blockIdx.x * blockDim.x + threadIdx.x) >> 6);
    const int l   = w >> (6 + SCL);
    const int rem = w & ((64 << SCL) - 1);
    const int sb  = rem >> SCL;
    const int sc  = rem & ((1 << SCL) - 1);

    const int r  = lane & 15;
    const int kg = lane >> 4;

    const int i = idxt[sb * 16 + r];
    const float4 sq = sQ[i];
    const float E1 = sq.x, E2 = sq.y, th = sq.z;

    const int j0 = sc * (NN >> SCL);
    const int* __restrict__ arow = (l ? adj2 : adj1) + (size_t)i * NN + j0 + kg * 8;
    const float* __restrict__ d1p = dE1 + j0 + kg * 8;
    const float* __restrict__ d2p = dE2 + j0 + kg * 8;
    const unsigned short* __restrict__ vbase =
        Vt2 + (((size_t)j0 >> 3) << 9) + ((size_t)kg << 9) + (r << 3);

    // ---- adj preload: issue all NT*2 loads, then compress to bits ----
    i32x4 am0[NT], am1[NT];
#pragma unroll
    for (int t = 0; t < NT; ++t) {
        am0[t] = *(const i32x4*)(arow + t * 32);
        am1[t] = *(const i32x4*)(arow + t * 32 + 4);
    }
    unsigned mbits[NT];
#pragma unroll
    for (int t = 0; t < NT; ++t) {
        unsigned m = 0;
#pragma unroll
        for (int e = 0; e < 4; ++e) {
            m |= (am0[t][e] != 0 ? 1u : 0u) << e;
            m |= (am1[t][e] != 0 ? 1u : 0u) << (4 + e);
        }
        mbits[t] = m;
    }

    short8 bOnes;
#pragma unroll
    for (int e = 0; e < 8; ++e) bOnes[e] = (short)0x3F80;   // bf16 1.0

    f32x4 acc0 = {0.f, 0.f, 0.f, 0.f};
    f32x4 acc1 = acc0, acc2 = acc0, acc3 = acc0, accz = acc0;

    TileS tA, tB;

#define LOADT(T, JT) do { const int _jr = (JT) * 32;                           \
    T.a0 = *(const f32x4*)(d1p + _jr);                                         \
    T.a1 = *(const f32x4*)(d1p + _jr + 4);                                     \
    T.b0 = *(const f32x4*)(d2p + _jr);                                         \
    T.b1 = *(const f32x4*)(d2p + _jr + 4);                                     \
    const unsigned short* _vp = vbase + ((size_t)(JT) << 11);                  \
    T.v0 = *(const short8*)(_vp);                                              \
    T.v1 = *(const short8*)(_vp + 128);                                        \
    T.v2 = *(const short8*)(_vp + 256);                                        \
    T.v3 = *(const short8*)(_vp + 384);                                        \
} while (0)

#define COMPT(T, JT) do {                                                      \
    const unsigned _mb = mbits[JT];                                            \
    short8 af;                                                                 \
    _Pragma("unroll")                                                          \
    for (int e = 0; e < 8; ++e) {                                              \
        const float e1 = (e < 4) ? T.a0[e & 3] : T.a1[e & 3];                  \
        const float e2 = (e < 4) ? T.b0[e & 3] : T.b1[e & 3];                  \
        const bool pos = e1 > th;                                              \
        float p = (pos ? e1 : e2) * (pos ? E1 : E2);                           \
        p = ((_mb >> e) & 1u) ? p : 0.f;                                       \
        af[e] = (short)f2bf(p);                                                \
    }                                                                          \
    acc0 = __builtin_amdgcn_mfma_f32_16x16x32_bf16(af, T.v0, acc0, 0, 0, 0);   \
    acc1 = __builtin_amdgcn_mfma_f32_16x16x32_bf16(af, T.v1, acc1, 0, 0, 0);   \
    acc2 = __builtin_amdgcn_mfma_f32_16x16x32_bf16(af, T.v2, acc2, 0, 0, 0);   \
    acc3 = __builtin_amdgcn_mfma_f32_16x16x32_bf16(af, T.v3, acc3, 0, 0, 0);   \
    accz = __builtin_amdgcn_mfma_f32_16x16x32_bf16(af, bOnes, accz, 0, 0, 0);  \
} while (0)

    LOADT(tA, 0);
#pragma unroll
    for (int jt = 0; jt < NT - 2; jt += 2) {
        LOADT(tB, jt + 1);
        COMPT(tA, jt);
        LOADT(tA, jt + 2);
        COMPT(tB, jt + 1);
    }
    LOADT(tB, NT - 1);
    COMPT(tA, NT - 2);
    COMPT(tB, NT - 1);
#undef LOADT
#undef COMPT

    // D layout: n-col = r (class), m-row = kg*4+q (sample within block).
    constexpr int SC = 1 << SCL;
#pragma unroll
    for (int q = 0; q < 4; ++q) {
        const int ks = sb * 16 + kg * 4 + q;
        const size_t slot = ((size_t)ks * 2 + l) * SC + sc;
        float* op = numPart + slot * CDIM + r;
        op[0]  = acc0[q];
        op[16] = acc1[q];
        op[32] = acc2[q];
        op[48] = acc3[q];
        if (r == 0) zPart[slot] = accz[q];
    }
}

// ---------------------------------------------------------------------------
// Kernel C: per-sample loss. One wave per sample k, lane = class. Partials for
// (k,l) contiguous; z via lane-parallel load + butterfly. h = 0.5*(relu(n1/z1)
// + relu(n2/z2)); log-softmax over 64 lanes; NLL.
// ---------------------------------------------------------------------------
__global__ __launch_bounds__(256) void k_loss(
    const float* __restrict__ numPart, const float* __restrict__ zPart,
    const int* __restrict__ labels, const int* __restrict__ idxt,
    float* __restrict__ losses, const int scLog2)
{
    const int lane = threadIdx.x & 63;
    const int k = (int)((blockIdx.x * blockDim.x + threadIdx.x) >> 6);
    const int SC = 1 << scLog2;

    float logit = 0.f;
#pragma unroll
    for (int l = 0; l < 2; ++l) {
        const size_t base = ((size_t)k * 2 + l) * SC;
        float ns = 0.f;
#pragma unroll 8
        for (int s = 0; s < SC; ++s)
            ns += numPart[(base + s) * CDIM + lane];
        float zs = (lane < SC) ? zPart[base + lane] : 0.f;
#pragma unroll
        for (int off = 32; off; off >>= 1) zs += __shfl_xor(zs, off);
        logit += fmaxf(ns / zs, 0.f);   // relu(elu(x)) == relu(x)
    }
    logit *= 0.5f;

    float m = logit;
#pragma unroll
    for (int off = 32; off; off >>= 1) m = fmaxf(m, __shfl_xor(m, off));
    float ex = __expf(logit - m);
    float sum = ex;
#pragma unroll
    for (int off = 32; off; off >>= 1) sum += __shfl_xor(sum, off);
    const float logp = logit - m - __logf(sum);

    const int y = labels[idxt[k]];
    const float t = __shfl(logp, y);
    if (lane == 0) losses[k] = -t;
}

// ---------------------------------------------------------------------------
// Kernel D: mean of 1024 per-sample losses -> d_out[0].
// ---------------------------------------------------------------------------
__global__ __launch_bounds__(256) void k_reduce(
    const float* __restrict__ losses, float* __restrict__ out)
{
    __shared__ float sbuf[4];
    const int tid = threadIdx.x;
    float v = losses[tid] + losses[tid + 256] + losses[tid + 512] + losses[tid + 768];
#pragma unroll
    for (int off = 32; off; off >>= 1) v += __shfl_xor(v, off);
    if ((tid & 63) == 0) sbuf[tid >> 6] = v;
    __syncthreads();
    if (tid == 0) out[0] = (sbuf[0] + sbuf[1] + sbuf[2] + sbuf[3]) * (1.f / 1024.f);
}

// ---------------------------------------------------------------------------
extern "C" void kernel_launch(void* const* d_in, const int* in_sizes, int n_in,
                              void* d_out, int out_size, void* d_ws, size_t ws_size,
                              hipStream_t stream)
{
    const float* feat   = (const float*)d_in[0];
    const float* W      = (const float*)d_in[1];
    const float* av     = (const float*)d_in[2];
    const int*   adj1   = (const int*)d_in[3];
    const int*   adj2   = (const int*)d_in[4];
    const int*   labels = (const int*)d_in[5];
    const int*   idxt   = (const int*)d_in[6];

    const size_t HEAD = (1u << 20) + (192u << 10);  // Vt2 1MB + sQ 128KB + dE1/2 64KB

    auto needed = [&](int scl) -> size_t {
        const size_t SC = (size_t)1 << scl;
        return HEAD + 2 * SC * NTRAIN * CDIM * sizeof(float)
                    + 2 * SC * NTRAIN * sizeof(float)
                    + NTRAIN * sizeof(float);
    };
    int scLog2 = (ws_size >= needed(5)) ? 5 : 4;   // NT=8 primary, NT=16 fallback
    const int SC = 1 << scLog2;

    char* ws = (char*)d_ws;
    unsigned short* Vt2 = (unsigned short*)ws;                  // 1 MB
    float4* sQ  = (float4*)(ws + (1u << 20));                   // 128 KB
    float*  dE1 = (float*)(ws + (1u << 20) + (128u << 10));     // 32 KB
    float*  dE2 = (float*)(ws + (1u << 20) + (160u << 10));     // 32 KB
    float*  numPart = (float*)(ws + HEAD);
    float*  zPart   = numPart + 2ull * SC * NTRAIN * CDIM;
    float*  losses  = zPart + 2ull * SC * NTRAIN;

    hipLaunchKernelGGL(k_wh, dim3(256), dim3(256), 0, stream,
                       feat, W, av, Vt2, sQ, dE1, dE2);
    if (scLog2 == 5)
        hipLaunchKernelGGL((k_mattn<5>), dim3(32 * 32), dim3(256), 0, stream,
                           adj1, adj2, Vt2, sQ, dE1, dE2, idxt, numPart, zPart);
    else
        hipLaunchKernelGGL((k_mattn<4>), dim3(32 * 16), dim3(256), 0, stream,
                           adj1, adj2, Vt2, sQ, dE1, dE2, idxt, numPart, zPart);
    hipLaunchKernelGGL(k_loss, dim3(NTRAIN / 4), dim3(256), 0, stream,
                       numPart, zPart, labels, idxt, losses, scLog2);
    hipLaunchKernelGGL(k_reduce, dim3(1), dim3(256), 0, stream,
                       losses, (float*)d_out);
}